// Round 1
// baseline (1506.017 us; speedup 1.0000x reference)
//
#include <hip/hip_runtime.h>

#define TT 8
#define NN 50000
#define FF 128
#define HH 64
#define CC 4
#define EE 800000

typedef unsigned short u16;

static __device__ __forceinline__ float bf2f(u16 u) {
    union { unsigned int i; float f; } v; v.i = ((unsigned int)u) << 16; return v.f;
}
static __device__ __forceinline__ u16 f2bf(float f) {
    union { float f; unsigned int u; } v; v.f = f;
    unsigned int u = v.u;
    unsigned int r = u + 0x7fffu + ((u >> 16) & 1u);   // round-to-nearest-even
    return (u16)(r >> 16);
}

// ---------------- histogram of edge destinations (in-degree, no self loop) ----------------
__global__ __launch_bounds__(256) void hist_kernel(const int* __restrict__ edges, int* __restrict__ cnt) {
    int t = blockIdx.y;
    int e = blockIdx.x * 256 + threadIdx.x;
    if (e < EE) {
        int dst = edges[(t * 2 + 1) * EE + e];
        atomicAdd(&cnt[t * NN + dst], 1);
    }
}

// ---------------- 2-level exclusive scan: per-256-chunk partial sums ----------------
__global__ __launch_bounds__(256) void scan_partial_kernel(const int* __restrict__ cnt, int* __restrict__ partials) {
    int t = blockIdx.y, cb = blockIdx.x, tid = threadIdx.x;
    int i = cb * 256 + tid;
    int v = (i < NN) ? cnt[t * NN + i] : 0;
    __shared__ int s[256];
    s[tid] = v; __syncthreads();
    for (int off = 128; off > 0; off >>= 1) {
        if (tid < off) s[tid] += s[tid + off];
        __syncthreads();
    }
    if (tid == 0) partials[t * 200 + cb] = s[0];
}

// scan the 196 partials per t (exclusive, in place); also write offs[N]=E
__global__ __launch_bounds__(256) void scan_top_kernel(int* __restrict__ partials, int* __restrict__ offs) {
    int t = blockIdx.x, tid = threadIdx.x;
    __shared__ int s[256];
    int v = (tid < 196) ? partials[t * 200 + tid] : 0;
    s[tid] = v; __syncthreads();
    for (int off = 1; off < 256; off <<= 1) {
        int x = 0;
        if (tid >= off) x = s[tid - off];
        __syncthreads();
        s[tid] += x;
        __syncthreads();
    }
    if (tid < 196) partials[t * 200 + tid] = s[tid] - v;   // exclusive
    if (tid == 0) offs[t * (NN + 1) + NN] = EE;
}

// final: per-element exclusive offsets + cursor init
__global__ __launch_bounds__(256) void scan_final_kernel(const int* __restrict__ cnt, const int* __restrict__ partials,
                                                         int* __restrict__ offs, int* __restrict__ cursor) {
    int t = blockIdx.y, cb = blockIdx.x, tid = threadIdx.x;
    int i = cb * 256 + tid;
    int v = (i < NN) ? cnt[t * NN + i] : 0;
    __shared__ int s[256];
    s[tid] = v; __syncthreads();
    for (int off = 1; off < 256; off <<= 1) {
        int x = 0;
        if (tid >= off) x = s[tid - off];
        __syncthreads();
        s[tid] += x;
        __syncthreads();
    }
    int excl = s[tid] - v + partials[t * 200 + cb];
    if (i < NN) {
        offs[t * (NN + 1) + i] = excl;
        cursor[t * NN + i] = excl;
    }
}

// ---------------- CSR fill: srclist grouped by dst ----------------
__global__ __launch_bounds__(256) void fill_kernel(const int* __restrict__ edges, int* __restrict__ cursor,
                                                   int* __restrict__ srclist) {
    int t = blockIdx.y;
    int e = blockIdx.x * 256 + threadIdx.x;
    if (e < EE) {
        int src = edges[(t * 2 + 0) * EE + e];
        int dst = edges[(t * 2 + 1) * EE + e];
        int p = atomicAdd(&cursor[t * NN + dst], 1);
        srclist[t * EE + p] = src;
    }
}

// ---------------- y = (x @ Wg) * dinv  (per timestep), stored bf16 ----------------
// block: 256 threads, 64 rows x 64 cols; thread tile 4x4. x tile in LDS (stride 132,
// conflict-free float4 broadcast reads); W read from global (L2-resident, 32KB per t).
__global__ __launch_bounds__(256) void xw_kernel(const float* __restrict__ x, const float* __restrict__ Wg,
                                                 const int* __restrict__ cnt, float* __restrict__ dinv,
                                                 u16* __restrict__ y) {
    int t = blockIdx.y;
    int row0 = blockIdx.x * 64;
    int tid = threadIdx.x;
    __shared__ __align__(16) float xs[64 * 132];
    __shared__ float ds[64];
    const float* xt = x + (size_t)t * NN * FF;
    // stage x tile (64 rows x 128 cols)
    #pragma unroll
    for (int it = 0; it < 32; ++it) {
        int idx = it * 256 + tid;
        int r = idx >> 7, k = idx & 127;
        int row = row0 + r;
        xs[r * 132 + k] = (row < NN) ? xt[(size_t)row * FF + k] : 0.f;
    }
    if (tid < 64) {
        int row = row0 + tid;
        float d = 0.f;
        if (row < NN) {
            d = rsqrtf(1.0f + (float)cnt[t * NN + row]);
            dinv[t * NN + row] = d;
        }
        ds[tid] = d;
    }
    __syncthreads();

    int c0 = (tid & 15) << 2;
    int r0 = (tid >> 4) << 2;
    const float* wgt = Wg + t * FF * HH;
    float s[4][4] = {};
    #pragma unroll 4
    for (int k0 = 0; k0 < 128; k0 += 4) {
        float4 xr[4], wr[4];
        #pragma unroll
        for (int j = 0; j < 4; ++j) xr[j] = *reinterpret_cast<const float4*>(&xs[(r0 + j) * 132 + k0]);
        #pragma unroll
        for (int j = 0; j < 4; ++j) wr[j] = *reinterpret_cast<const float4*>(&wgt[(k0 + j) * 64 + c0]);
        #pragma unroll
        for (int kk = 0; kk < 4; ++kk) {
            float wx = wr[kk].x, wy = wr[kk].y, wz = wr[kk].z, ww = wr[kk].w;
            #pragma unroll
            for (int r = 0; r < 4; ++r) {
                float xv = (kk == 0) ? xr[r].x : (kk == 1) ? xr[r].y : (kk == 2) ? xr[r].z : xr[r].w;
                s[r][0] += xv * wx;
                s[r][1] += xv * wy;
                s[r][2] += xv * wz;
                s[r][3] += xv * ww;
            }
        }
    }
    #pragma unroll
    for (int j = 0; j < 4; ++j) {
        int row = row0 + r0 + j;
        if (row < NN) {
            float dv = ds[r0 + j];
            ushort4 pk;
            pk.x = f2bf(s[j][0] * dv);
            pk.y = f2bf(s[j][1] * dv);
            pk.z = f2bf(s[j][2] * dv);
            pk.w = f2bf(s[j][3] * dv);
            *reinterpret_cast<ushort4*>(&y[((size_t)t * NN + row) * HH + c0]) = pk;
        }
    }
}

// ---------------- gather-aggregate over all T, relu-accumulate ----------------
// one wave per node; lane = feature column
__global__ __launch_bounds__(256) void agg_kernel(const u16* __restrict__ y, const float* __restrict__ dinv,
                                                  const int* __restrict__ offs, const int* __restrict__ srclist,
                                                  const float* __restrict__ bg, float* __restrict__ acc) {
    int node = blockIdx.x * 4 + (threadIdx.x >> 6);
    int lane = threadIdx.x & 63;
    if (node >= NN) return;
    float a = 0.f;
    for (int t = 0; t < TT; ++t) {
        const u16* yt = y + (size_t)t * NN * HH;
        float s = bf2f(yt[(size_t)node * HH + lane]);   // self loop term (y already scaled by dinv)
        int beg = offs[t * (NN + 1) + node];
        int end = offs[t * (NN + 1) + node + 1];
        const int* sl = srclist + t * EE;
        for (int j = beg; j < end; ++j) {
            int src = sl[j];
            s += bf2f(yt[(size_t)src * HH + lane]);
        }
        float v = dinv[t * NN + node] * s + bg[t * HH + lane];
        a += fmaxf(v, 0.f);
    }
    acc[(size_t)node * HH + lane] = a;
}

// ---------------- per-node MLP head + log_softmax ----------------
__global__ __launch_bounds__(256) void head_kernel(const float* __restrict__ acc,
                                                   const float* __restrict__ W1, const float* __restrict__ b1,
                                                   const float* __restrict__ W2, const float* __restrict__ b2,
                                                   const float* __restrict__ W3, const float* __restrict__ b3,
                                                   float* __restrict__ out) {
    __shared__ float w1[64 * 32], w2[32 * 16], w3[16 * 4], bb1[32], bb2[16], bb3[4];
    int tid = threadIdx.x;
    for (int i = tid; i < 2048; i += 256) w1[i] = W1[i];
    for (int i = tid; i < 512; i += 256) w2[i] = W2[i];
    if (tid < 64) w3[tid] = W3[tid];
    if (tid < 32) bb1[tid] = b1[tid];
    if (tid < 16) bb2[tid] = b2[tid];
    if (tid < 4) bb3[tid] = b3[tid];
    __syncthreads();
    int node = blockIdx.x * 256 + tid;
    if (node >= NN) return;

    float a[64];
    #pragma unroll
    for (int k = 0; k < 64; ++k) a[k] = acc[(size_t)node * HH + k];

    float h1[32];
    for (int j = 0; j < 32; ++j) {
        float s = bb1[j];
        #pragma unroll
        for (int k = 0; k < 64; ++k) s += a[k] * w1[k * 32 + j];
        h1[j] = fmaxf(s, 0.f);
    }
    float h2[16];
    for (int j = 0; j < 16; ++j) {
        float s = bb2[j];
        #pragma unroll
        for (int k = 0; k < 32; ++k) s += h1[k] * w2[k * 16 + j];
        h2[j] = fmaxf(s, 0.f);
    }
    float l[4];
    for (int c = 0; c < 4; ++c) {
        float s = bb3[c];
        #pragma unroll
        for (int k = 0; k < 16; ++k) s += h2[k] * w3[k * 4 + c];
        l[c] = s;
    }
    float m = fmaxf(fmaxf(l[0], l[1]), fmaxf(l[2], l[3]));
    float sum = 0.f;
    #pragma unroll
    for (int c = 0; c < 4; ++c) sum += expf(l[c] - m);
    float lse = logf(sum);
    float4 o;
    o.x = l[0] - m - lse; o.y = l[1] - m - lse; o.z = l[2] - m - lse; o.w = l[3] - m - lse;
    *reinterpret_cast<float4*>(&out[(size_t)node * CC]) = o;
}

extern "C" void kernel_launch(void* const* d_in, const int* in_sizes, int n_in,
                              void* d_out, int out_size, void* d_ws, size_t ws_size,
                              hipStream_t stream) {
    const float* x   = (const float*)d_in[0];
    const int*  edges = (const int*)d_in[1];
    const float* Wg  = (const float*)d_in[2];
    const float* bg  = (const float*)d_in[3];
    const float* W1  = (const float*)d_in[4];
    const float* b1  = (const float*)d_in[5];
    const float* W2  = (const float*)d_in[6];
    const float* b2  = (const float*)d_in[7];
    const float* W3  = (const float*)d_in[8];
    const float* b3  = (const float*)d_in[9];
    float* out = (float*)d_out;

    char* ws = (char*)d_ws;
    size_t o = 0;
    int* cnt     = (int*)(ws + o); o += (size_t)TT * NN * 4;        // 1.6 MB
    int* offs    = (int*)(ws + o); o += (size_t)TT * (NN + 1) * 4;  // ~1.6 MB
    o = (o + 255) & ~(size_t)255;
    int* cursor  = (int*)(ws + o); o += (size_t)TT * NN * 4;        // 1.6 MB
    int* partials= (int*)(ws + o); o += (size_t)TT * 200 * 4;       // 6.4 KB
    o = (o + 255) & ~(size_t)255;
    float* dinv  = (float*)(ws + o); o += (size_t)TT * NN * 4;      // 1.6 MB
    int* srclist = (int*)(ws + o); o += (size_t)TT * EE * 4;        // 25.6 MB
    u16* y       = (u16*)(ws + o); o += (size_t)TT * NN * HH * 2;   // 51.2 MB
    float* acc   = (float*)(ws + o); o += (size_t)NN * HH * 4;      // 12.8 MB
    // total ~96 MB

    hipMemsetAsync(cnt, 0, (size_t)TT * NN * 4, stream);

    dim3 ge(3125, TT);
    hist_kernel<<<ge, 256, 0, stream>>>(edges, cnt);

    dim3 gs(196, TT);
    scan_partial_kernel<<<gs, 256, 0, stream>>>(cnt, partials);
    scan_top_kernel<<<TT, 256, 0, stream>>>(partials, offs);
    scan_final_kernel<<<gs, 256, 0, stream>>>(cnt, partials, offs, cursor);

    fill_kernel<<<ge, 256, 0, stream>>>(edges, cursor, srclist);

    dim3 gx(782, TT);
    xw_kernel<<<gx, 256, 0, stream>>>(x, Wg, cnt, dinv, y);

    agg_kernel<<<12500, 256, 0, stream>>>(y, dinv, offs, srclist, bg, acc);

    head_kernel<<<196, 256, 0, stream>>>(acc, W1, b1, W2, b2, W3, b3, out);
}

// Round 2
// 1058.133 us; speedup vs baseline: 1.4233x; 1.4233x over previous
//
#include <hip/hip_runtime.h>

#define TT 8
#define NN 50000
#define FF 128
#define HH 64
#define CC 4
#define EE 800000

typedef unsigned short u16;

static __device__ __forceinline__ float bf2f(u16 u) {
    union { unsigned int i; float f; } v; v.i = ((unsigned int)u) << 16; return v.f;
}
static __device__ __forceinline__ u16 f2bf(float f) {
    union { float f; unsigned int u; } v; v.f = f;
    unsigned int u = v.u;
    unsigned int r = u + 0x7fffu + ((u >> 16) & 1u);   // round-to-nearest-even
    return (u16)(r >> 16);
}

// ---------------- histogram of edge destinations (in-degree, no self loop) ----------------
// 1D grid, t = bid & 7: round-robin dispatch pins each timestep's atomics to one XCD's L2.
__global__ __launch_bounds__(256) void hist_kernel(const int* __restrict__ edges, int* __restrict__ cnt) {
    int bid = blockIdx.x;
    int t = bid & 7;
    int e = (bid >> 3) * 256 + threadIdx.x;
    if (e < EE) {
        int dst = edges[(t * 2 + 1) * EE + e];
        atomicAdd(&cnt[t * NN + dst], 1);
    }
}

// ---------------- 2-level exclusive scan: per-256-chunk partial sums ----------------
__global__ __launch_bounds__(256) void scan_partial_kernel(const int* __restrict__ cnt, int* __restrict__ partials) {
    int t = blockIdx.y, cb = blockIdx.x, tid = threadIdx.x;
    int i = cb * 256 + tid;
    int v = (i < NN) ? cnt[t * NN + i] : 0;
    __shared__ int s[256];
    s[tid] = v; __syncthreads();
    for (int off = 128; off > 0; off >>= 1) {
        if (tid < off) s[tid] += s[tid + off];
        __syncthreads();
    }
    if (tid == 0) partials[t * 200 + cb] = s[0];
}

// scan the 196 partials per t (exclusive, in place); also write offs[N]=E
__global__ __launch_bounds__(256) void scan_top_kernel(int* __restrict__ partials, int* __restrict__ offs) {
    int t = blockIdx.x, tid = threadIdx.x;
    __shared__ int s[256];
    int v = (tid < 196) ? partials[t * 200 + tid] : 0;
    s[tid] = v; __syncthreads();
    for (int off = 1; off < 256; off <<= 1) {
        int x = 0;
        if (tid >= off) x = s[tid - off];
        __syncthreads();
        s[tid] += x;
        __syncthreads();
    }
    if (tid < 196) partials[t * 200 + tid] = s[tid] - v;   // exclusive
    if (tid == 0) offs[t * (NN + 1) + NN] = EE;
}

// final: per-element exclusive offsets + cursor init
__global__ __launch_bounds__(256) void scan_final_kernel(const int* __restrict__ cnt, const int* __restrict__ partials,
                                                         int* __restrict__ offs, int* __restrict__ cursor) {
    int t = blockIdx.y, cb = blockIdx.x, tid = threadIdx.x;
    int i = cb * 256 + tid;
    int v = (i < NN) ? cnt[t * NN + i] : 0;
    __shared__ int s[256];
    s[tid] = v; __syncthreads();
    for (int off = 1; off < 256; off <<= 1) {
        int x = 0;
        if (tid >= off) x = s[tid - off];
        __syncthreads();
        s[tid] += x;
        __syncthreads();
    }
    int excl = s[tid] - v + partials[t * 200 + cb];
    if (i < NN) {
        offs[t * (NN + 1) + i] = excl;
        cursor[t * NN + i] = excl;
    }
}

// ---------------- CSR fill: srclist grouped by dst ----------------
// XCD-pinned per timestep: cursor (200KB) + srclist slice (3.2MB) stay in one XCD's 4MB L2,
// avoiding the 64B-line writeback thrash of the scattered 4B stores.
__global__ __launch_bounds__(256) void fill_kernel(const int* __restrict__ edges, int* __restrict__ cursor,
                                                   int* __restrict__ srclist) {
    int bid = blockIdx.x;
    int t = bid & 7;
    int e = (bid >> 3) * 256 + threadIdx.x;
    if (e < EE) {
        int src = edges[(t * 2 + 0) * EE + e];
        int dst = edges[(t * 2 + 1) * EE + e];
        int p = atomicAdd(&cursor[t * NN + dst], 1);
        srclist[t * EE + p] = src;
    }
}

// ---------------- y = (x @ Wg) * dinv  (per timestep), stored bf16 ----------------
__global__ __launch_bounds__(256) void xw_kernel(const float* __restrict__ x, const float* __restrict__ Wg,
                                                 const int* __restrict__ cnt, float* __restrict__ dinv,
                                                 u16* __restrict__ y) {
    int t = blockIdx.y;
    int row0 = blockIdx.x * 64;
    int tid = threadIdx.x;
    __shared__ __align__(16) float xs[64 * 132];
    __shared__ float ds[64];
    const float* xt = x + (size_t)t * NN * FF;
    #pragma unroll
    for (int it = 0; it < 32; ++it) {
        int idx = it * 256 + tid;
        int r = idx >> 7, k = idx & 127;
        int row = row0 + r;
        xs[r * 132 + k] = (row < NN) ? xt[(size_t)row * FF + k] : 0.f;
    }
    if (tid < 64) {
        int row = row0 + tid;
        float d = 0.f;
        if (row < NN) {
            d = rsqrtf(1.0f + (float)cnt[t * NN + row]);
            dinv[t * NN + row] = d;
        }
        ds[tid] = d;
    }
    __syncthreads();

    int c0 = (tid & 15) << 2;
    int r0 = (tid >> 4) << 2;
    const float* wgt = Wg + t * FF * HH;
    float s[4][4] = {};
    #pragma unroll 4
    for (int k0 = 0; k0 < 128; k0 += 4) {
        float4 xr[4], wr[4];
        #pragma unroll
        for (int j = 0; j < 4; ++j) xr[j] = *reinterpret_cast<const float4*>(&xs[(r0 + j) * 132 + k0]);
        #pragma unroll
        for (int j = 0; j < 4; ++j) wr[j] = *reinterpret_cast<const float4*>(&wgt[(k0 + j) * 64 + c0]);
        #pragma unroll
        for (int kk = 0; kk < 4; ++kk) {
            float wx = wr[kk].x, wy = wr[kk].y, wz = wr[kk].z, ww = wr[kk].w;
            #pragma unroll
            for (int r = 0; r < 4; ++r) {
                float xv = (kk == 0) ? xr[r].x : (kk == 1) ? xr[r].y : (kk == 2) ? xr[r].z : xr[r].w;
                s[r][0] += xv * wx;
                s[r][1] += xv * wy;
                s[r][2] += xv * wz;
                s[r][3] += xv * ww;
            }
        }
    }
    #pragma unroll
    for (int j = 0; j < 4; ++j) {
        int row = row0 + r0 + j;
        if (row < NN) {
            float dv = ds[r0 + j];
            ushort4 pk;
            pk.x = f2bf(s[j][0] * dv);
            pk.y = f2bf(s[j][1] * dv);
            pk.z = f2bf(s[j][2] * dv);
            pk.w = f2bf(s[j][3] * dv);
            *reinterpret_cast<ushort4*>(&y[((size_t)t * NN + row) * HH + c0]) = pk;
        }
    }
}

// ---------------- gather-aggregate over all T, relu-accumulate ----------------
// one wave per node; lane = feature column. Inner CSR loop unrolled x8 so 8 independent
// row-gathers are in flight per wait (was 1 -> latency-bound at 17% VALUBusy).
__global__ __launch_bounds__(256) void agg_kernel(const u16* __restrict__ y, const float* __restrict__ dinv,
                                                  const int* __restrict__ offs, const int* __restrict__ srclist,
                                                  const float* __restrict__ bg, float* __restrict__ acc) {
    int node = blockIdx.x * 4 + (threadIdx.x >> 6);
    int lane = threadIdx.x & 63;
    if (node >= NN) return;
    float a = 0.f;
    for (int t = 0; t < TT; ++t) {
        const u16* yt = y + (size_t)t * NN * HH;
        float s = bf2f(yt[(size_t)node * HH + lane]);   // self loop term (y already scaled by dinv)
        int beg = offs[t * (NN + 1) + node];
        int end = offs[t * (NN + 1) + node + 1];
        const int* sl = srclist + t * EE;
        int j = beg;
        for (; j + 8 <= end; j += 8) {
            int i0 = sl[j + 0], i1 = sl[j + 1], i2 = sl[j + 2], i3 = sl[j + 3];
            int i4 = sl[j + 4], i5 = sl[j + 5], i6 = sl[j + 6], i7 = sl[j + 7];
            float v0 = bf2f(yt[(size_t)i0 * HH + lane]);
            float v1 = bf2f(yt[(size_t)i1 * HH + lane]);
            float v2 = bf2f(yt[(size_t)i2 * HH + lane]);
            float v3 = bf2f(yt[(size_t)i3 * HH + lane]);
            float v4 = bf2f(yt[(size_t)i4 * HH + lane]);
            float v5 = bf2f(yt[(size_t)i5 * HH + lane]);
            float v6 = bf2f(yt[(size_t)i6 * HH + lane]);
            float v7 = bf2f(yt[(size_t)i7 * HH + lane]);
            s += ((v0 + v1) + (v2 + v3)) + ((v4 + v5) + (v6 + v7));
        }
        if (j + 4 <= end) {
            int i0 = sl[j + 0], i1 = sl[j + 1], i2 = sl[j + 2], i3 = sl[j + 3];
            float v0 = bf2f(yt[(size_t)i0 * HH + lane]);
            float v1 = bf2f(yt[(size_t)i1 * HH + lane]);
            float v2 = bf2f(yt[(size_t)i2 * HH + lane]);
            float v3 = bf2f(yt[(size_t)i3 * HH + lane]);
            s += (v0 + v1) + (v2 + v3);
            j += 4;
        }
        for (; j < end; ++j) {
            s += bf2f(yt[(size_t)sl[j] * HH + lane]);
        }
        float v = dinv[t * NN + node] * s + bg[t * HH + lane];
        a += fmaxf(v, 0.f);
    }
    acc[(size_t)node * HH + lane] = a;
}

// ---------------- per-node MLP head + log_softmax ----------------
__global__ __launch_bounds__(256) void head_kernel(const float* __restrict__ acc,
                                                   const float* __restrict__ W1, const float* __restrict__ b1,
                                                   const float* __restrict__ W2, const float* __restrict__ b2,
                                                   const float* __restrict__ W3, const float* __restrict__ b3,
                                                   float* __restrict__ out) {
    __shared__ float w1[64 * 32], w2[32 * 16], w3[16 * 4], bb1[32], bb2[16], bb3[4];
    int tid = threadIdx.x;
    for (int i = tid; i < 2048; i += 256) w1[i] = W1[i];
    for (int i = tid; i < 512; i += 256) w2[i] = W2[i];
    if (tid < 64) w3[tid] = W3[tid];
    if (tid < 32) bb1[tid] = b1[tid];
    if (tid < 16) bb2[tid] = b2[tid];
    if (tid < 4) bb3[tid] = b3[tid];
    __syncthreads();
    int node = blockIdx.x * 256 + tid;
    if (node >= NN) return;

    float a[64];
    #pragma unroll
    for (int k = 0; k < 64; ++k) a[k] = acc[(size_t)node * HH + k];

    float h1[32];
    for (int j = 0; j < 32; ++j) {
        float s = bb1[j];
        #pragma unroll
        for (int k = 0; k < 64; ++k) s += a[k] * w1[k * 32 + j];
        h1[j] = fmaxf(s, 0.f);
    }
    float h2[16];
    for (int j = 0; j < 16; ++j) {
        float s = bb2[j];
        #pragma unroll
        for (int k = 0; k < 32; ++k) s += h1[k] * w2[k * 16 + j];
        h2[j] = fmaxf(s, 0.f);
    }
    float l[4];
    for (int c = 0; c < 4; ++c) {
        float s = bb3[c];
        #pragma unroll
        for (int k = 0; k < 16; ++k) s += h2[k] * w3[k * 4 + c];
        l[c] = s;
    }
    float m = fmaxf(fmaxf(l[0], l[1]), fmaxf(l[2], l[3]));
    float sum = 0.f;
    #pragma unroll
    for (int c = 0; c < 4; ++c) sum += expf(l[c] - m);
    float lse = logf(sum);
    float4 o;
    o.x = l[0] - m - lse; o.y = l[1] - m - lse; o.z = l[2] - m - lse; o.w = l[3] - m - lse;
    *reinterpret_cast<float4*>(&out[(size_t)node * CC]) = o;
}

extern "C" void kernel_launch(void* const* d_in, const int* in_sizes, int n_in,
                              void* d_out, int out_size, void* d_ws, size_t ws_size,
                              hipStream_t stream) {
    const float* x   = (const float*)d_in[0];
    const int*  edges = (const int*)d_in[1];
    const float* Wg  = (const float*)d_in[2];
    const float* bg  = (const float*)d_in[3];
    const float* W1  = (const float*)d_in[4];
    const float* b1  = (const float*)d_in[5];
    const float* W2  = (const float*)d_in[6];
    const float* b2  = (const float*)d_in[7];
    const float* W3  = (const float*)d_in[8];
    const float* b3  = (const float*)d_in[9];
    float* out = (float*)d_out;

    char* ws = (char*)d_ws;
    size_t o = 0;
    int* cnt     = (int*)(ws + o); o += (size_t)TT * NN * 4;        // 1.6 MB
    int* offs    = (int*)(ws + o); o += (size_t)TT * (NN + 1) * 4;  // ~1.6 MB
    o = (o + 255) & ~(size_t)255;
    int* cursor  = (int*)(ws + o); o += (size_t)TT * NN * 4;        // 1.6 MB
    int* partials= (int*)(ws + o); o += (size_t)TT * 200 * 4;       // 6.4 KB
    o = (o + 255) & ~(size_t)255;
    float* dinv  = (float*)(ws + o); o += (size_t)TT * NN * 4;      // 1.6 MB
    int* srclist = (int*)(ws + o); o += (size_t)TT * EE * 4;        // 25.6 MB
    u16* y       = (u16*)(ws + o); o += (size_t)TT * NN * HH * 2;   // 51.2 MB
    float* acc   = (float*)(ws + o); o += (size_t)NN * HH * 4;      // 12.8 MB
    // total ~96 MB

    hipMemsetAsync(cnt, 0, (size_t)TT * NN * 4, stream);

    // 1D grids with t = bid & 7 -> XCD-pinned per timestep
    hist_kernel<<<3125 * TT, 256, 0, stream>>>(edges, cnt);

    dim3 gs(196, TT);
    scan_partial_kernel<<<gs, 256, 0, stream>>>(cnt, partials);
    scan_top_kernel<<<TT, 256, 0, stream>>>(partials, offs);
    scan_final_kernel<<<gs, 256, 0, stream>>>(cnt, partials, offs, cursor);

    fill_kernel<<<3125 * TT, 256, 0, stream>>>(edges, cursor, srclist);

    dim3 gx(782, TT);
    xw_kernel<<<gx, 256, 0, stream>>>(x, Wg, cnt, dinv, y);

    agg_kernel<<<12500, 256, 0, stream>>>(y, dinv, offs, srclist, bg, acc);

    head_kernel<<<196, 256, 0, stream>>>(acc, W1, b1, W2, b2, W3, b3, out);
}